// Round 11
// baseline (657.246 us; speedup 1.0000x reference)
//
#include <hip/hip_runtime.h>
#include <math.h>

#define TPB 256
#define TPB_P 512
#define TPB_A 512            // k_agg: 64KB acc -> 2 blocks/CU, 16 waves/CU (R4 measured best)
#define LRATE 0.005f

// Final bucketing: 1024 nodes per bucket (round-4 measured optimum)
#define LOG_NPB 10
#define NPB (1 << LOG_NPB)
#define CAP 14336            // mean ~10225 edges/bucket; +40 sigma

// Two-level partition (r5 lesson: short scatter runs -> 4x write amp)
#define LOG_SUP 13
#define NS1 64               // level-1 bins: dst>>13
#define CAP1 90112           // 22*4096; mean 81920, +28 sigma
#define NS2 8                // level-2 bins
#define CHUNK 4096
#define CPT (CHUNK / TPB_P)  // 8
#define R1 4                 // hist/cursor replication (part1)
#define R2 8                 // (part2)
#define RS 4                 // (sort)
#define NTILE 64             // src-tile = src>>13 == rec>>23

// fixed-point scale (LDS int atomics native; float LDS atomicAdd = CAS loop)
#define FXS  65536.0f
#define FXSI (1.0f / 65536.0f)
#define FXBIAS (1 << 20)     // per-addend bias: positive halves, no carry

// ---------------------------------------------------------------------------
#if __has_builtin(__builtin_amdgcn_cvt_f32_fp8) && __has_builtin(__builtin_amdgcn_cvt_pk_fp8_f32)
__device__ __forceinline__ float fp8_dec(unsigned char v) {
    return __builtin_amdgcn_cvt_f32_fp8((int)v, 0);
}
__device__ __forceinline__ unsigned fp8_pk4(float a, float b, float c, float d) {
    int w = __builtin_amdgcn_cvt_pk_fp8_f32(a, b, 0, false);
    w = __builtin_amdgcn_cvt_pk_fp8_f32(c, d, w, true);
    return (unsigned)w;
}
#else
__device__ __forceinline__ unsigned char fp8_enc1(float f) {
    unsigned u = __float_as_uint(f);
    unsigned s = (u >> 24) & 0x80u;
    u &= 0x7FFFFFFFu;
    if (u >= 0x43E00000u) return (unsigned char)(s | 0x7E);
    if (u < 0x3C800000u) {
        float a = __uint_as_float(u);
        int m = (int)rintf(a * 512.f);
        return (unsigned char)(s | (unsigned)m);
    }
    unsigned mant = u & 0x7FFFFFu;
    unsigned rest = mant & 0xFFFFFu;
    unsigned keep = u >> 20;
    keep += (rest > 0x80000u || (rest == 0x80000u && (keep & 1u))) ? 1u : 0u;
    int eb = (int)(keep >> 3) - 127 + 7;
    return (unsigned char)(s | (unsigned)((eb << 3) | (int)(keep & 7u)));
}
__device__ __forceinline__ float fp8_dec(unsigned char v) {
    unsigned s = ((unsigned)(v & 0x80u)) << 24;
    unsigned e = (v >> 3) & 0xFu;
    unsigned m = v & 7u;
    if (e == 0) {
        float r = (float)m * 0.001953125f;
        return (v & 0x80u) ? -r : r;
    }
    return __uint_as_float(s | ((e + 120u) << 23) | (m << 20));
}
__device__ __forceinline__ unsigned fp8_pk4(float a, float b, float c, float d) {
    return (unsigned)fp8_enc1(a) | ((unsigned)fp8_enc1(b) << 8) |
           ((unsigned)fp8_enc1(c) << 16) | ((unsigned)fp8_enc1(d) << 24);
}
#endif

#if __has_builtin(__builtin_amdgcn_cvt_pk_f32_fp8)
typedef float __attribute__((ext_vector_type(2))) f32x2;
__device__ __forceinline__ void fp8_dec4(unsigned w, float& a, float& b, float& c, float& d) {
    f32x2 lo = __builtin_amdgcn_cvt_pk_f32_fp8((int)w, false);
    f32x2 hi = __builtin_amdgcn_cvt_pk_f32_fp8((int)w, true);
    a = lo[0]; b = lo[1]; c = hi[0]; d = hi[1];
}
#else
__device__ __forceinline__ void fp8_dec4(unsigned w, float& a, float& b, float& c, float& d) {
    a = fp8_dec((unsigned char)(w & 0xFFu));
    b = fp8_dec((unsigned char)((w >> 8) & 0xFFu));
    c = fp8_dec((unsigned char)((w >> 16) & 0xFFu));
    d = fp8_dec((unsigned char)((w >> 24) & 0xFFu));
}
#endif

__device__ __forceinline__ unsigned long long pack2(float f0, float f1) {
    unsigned lo = (unsigned)(FXBIAS + (int)(f0 * FXS));
    unsigned hi = (unsigned)(FXBIAS + (int)(f1 * FXS));
    return (unsigned long long)lo | ((unsigned long long)hi << 32);
}

// compute one fp8 hp row: hp[node] = fp8(di * xrow @ W^T), W in LDS
__device__ __forceinline__ uint4 hp_row(const float* __restrict__ xrow,
                                        const float* __restrict__ sW, float di) {
    float xv[16];
    const float4* xr = (const float4*)xrow;
#pragma unroll
    for (int q = 0; q < 4; q++) {
        float4 v = xr[q];
        xv[4*q+0] = v.x; xv[4*q+1] = v.y; xv[4*q+2] = v.z; xv[4*q+3] = v.w;
    }
    float hv[16];
#pragma unroll
    for (int j = 0; j < 16; j++) {
        float s = 0.f;
#pragma unroll
        for (int k = 0; k < 16; k++) s = fmaf(xv[k], sW[j*16 + k], s);
        hv[j] = di * s;
    }
    uint4 w;
    w.x = fp8_pk4(hv[0],  hv[1],  hv[2],  hv[3]);
    w.y = fp8_pk4(hv[4],  hv[5],  hv[6],  hv[7]);
    w.z = fp8_pk4(hv[8],  hv[9],  hv[10], hv[11]);
    w.w = fp8_pk4(hv[12], hv[13], hv[14], hv[15]);
    return w;
}

// ---------------------------------------------------------------------------
// K_PART1: level-1 partition by super-bucket (dst >> 13, 64 bins; x4 repl).
__global__ __launch_bounds__(TPB_P) void k_part1(const int* __restrict__ src,
                                                 const int* __restrict__ dst,
                                                 int* __restrict__ bcur1,
                                                 int* __restrict__ grec1,
                                                 int E) {
    __shared__ int hist[R1][NS1];
    __shared__ int lcur[R1][NS1];
    __shared__ int lstart[NS1], tot[NS1], gbase[NS1];
    __shared__ int lbuf[CHUNK];
    __shared__ unsigned char bbuf[CHUNK];
    int t = threadIdx.x;
    int g = t & (R1 - 1);
    int chunkBase = blockIdx.x * CHUNK;
    for (int i = t; i < R1 * NS1; i += TPB_P) (&hist[0][0])[i] = 0;
    __syncthreads();

    int myb[CPT], myrec[CPT];
#pragma unroll
    for (int k = 0; k < CPT; k++) {
        int e = chunkBase + k * TPB_P + t;
        if (e < E) {
            int d = dst[e];
            int s = src[e];
            myb[k] = d >> LOG_SUP;
            myrec[k] = (s << LOG_SUP) | (d & ((1 << LOG_SUP) - 1));
            atomicAdd(&hist[g][myb[k]], 1);
        } else myb[k] = -1;
    }
    __syncthreads();
    if (t < NS1) {
        int s = 0;
#pragma unroll
        for (int r = 0; r < R1; r++) s += hist[r][t];
        tot[t] = s;
    }
    __syncthreads();
    if (t == 0) {
        int run = 0;
        for (int b = 0; b < NS1; b++) { lstart[b] = run; run += tot[b]; }
    }
    __syncthreads();
    if (t < NS1) {
        int run = lstart[t];
#pragma unroll
        for (int r = 0; r < R1; r++) { lcur[r][t] = run; run += hist[r][t]; }
        if (tot[t] > 0) gbase[t] = atomicAdd(&bcur1[t * 16], tot[t]);
    }
    __syncthreads();
#pragma unroll
    for (int k = 0; k < CPT; k++) {
        if (myb[k] >= 0) {
            int p = atomicAdd(&lcur[g][myb[k]], 1);
            lbuf[p] = myrec[k];
            bbuf[p] = (unsigned char)myb[k];
        }
    }
    __syncthreads();
    int total = E - chunkBase; if (total > CHUNK) total = CHUNK;
    for (int p = t; p < total; p += TPB_P) {
        int b = (int)bbuf[p];
        int pos = gbase[b] + (p - lstart[b]);
        if (pos < CAP1) grec1[(size_t)b * CAP1 + pos] = lbuf[p];
    }
}

// K_PART2: level-2 partition of each super-bucket into its 8 final buckets.
__global__ __launch_bounds__(TPB_P) void k_part2(const int* __restrict__ bcur1,
                                                 const int* __restrict__ grec1,
                                                 int* __restrict__ bcur,
                                                 int* __restrict__ grecU) {
    __shared__ int hist[R2][NS2];
    __shared__ int lcur[R2][NS2];
    __shared__ int lstart[NS2], tot[NS2], gbase[NS2];
    __shared__ int lbuf[CHUNK];
    __shared__ unsigned char bbuf[CHUNK];
    int t = threadIdx.x;
    int g = t & (R2 - 1);
    int s = blockIdx.x;
    int cnt1 = bcur1[s * 16]; if (cnt1 > CAP1) cnt1 = CAP1;
    int chunkBase = blockIdx.y * CHUNK;
    if (chunkBase >= cnt1) return;             // uniform per block
    int total = cnt1 - chunkBase; if (total > CHUNK) total = CHUNK;
    for (int i = t; i < R2 * NS2; i += TPB_P) (&hist[0][0])[i] = 0;
    __syncthreads();

    int myb[CPT], myrec[CPT];
#pragma unroll
    for (int k = 0; k < CPT; k++) {
        int i = chunkBase + k * TPB_P + t;
        if (i < cnt1) {
            int r = grec1[(size_t)s * CAP1 + i];
            int sub = (r >> LOG_NPB) & (NS2 - 1);
            myb[k] = sub;
            myrec[k] = (int)((((unsigned)r) >> LOG_SUP) << LOG_NPB) | (r & (NPB - 1));
            atomicAdd(&hist[g][sub], 1);
        } else myb[k] = -1;
    }
    __syncthreads();
    if (t < NS2) {
        int c = 0;
#pragma unroll
        for (int r = 0; r < R2; r++) c += hist[r][t];
        tot[t] = c;
    }
    __syncthreads();
    if (t == 0) {
        int run = 0;
        for (int b = 0; b < NS2; b++) { lstart[b] = run; run += tot[b]; }
    }
    __syncthreads();
    if (t < NS2) {
        int run = lstart[t];
#pragma unroll
        for (int r = 0; r < R2; r++) { lcur[r][t] = run; run += hist[r][t]; }
        if (tot[t] > 0) gbase[t] = atomicAdd(&bcur[(s * NS2 + t) * 16], tot[t]);
    }
    __syncthreads();
#pragma unroll
    for (int k = 0; k < CPT; k++) {
        if (myb[k] >= 0) {
            int p = atomicAdd(&lcur[g][myb[k]], 1);
            lbuf[p] = myrec[k];
            bbuf[p] = (unsigned char)myb[k];
        }
    }
    __syncthreads();
    for (int p = t; p < total; p += TPB_P) {
        int b = (int)bbuf[p];
        int pos = gbase[b] + (p - lstart[b]);
        if (pos < CAP) grecU[(size_t)(s * NS2 + b) * CAP + pos] = lbuf[p];
    }
}

// K_SORT(+h0): per-bucket counting sort by src-tile, out-of-place
// grecU -> grec; then deg -> dinv AND layer-0 hp rows for own nodes
// (fuses the old k_h layer-0 dispatch: x rows and deg are per-node local).
__global__ __launch_bounds__(TPB_P) void k_sort(const int* __restrict__ bcur,
                                                const int* __restrict__ grecU,
                                                int* __restrict__ grec,
                                                float* __restrict__ dinv,
                                                const float* __restrict__ x,
                                                const float* __restrict__ W1,
                                                unsigned* __restrict__ hp, int N) {
    __shared__ int lbuf[CAP];     // 57344 B (sW overlays after scatter)
    __shared__ int deg[NPB];      // 4096 B
    __shared__ int hist[RS][NTILE];
    __shared__ int curp[RS][NTILE];
    __shared__ int lstart[NTILE], tot[NTILE];
    int t = threadIdx.x;
    int g = t & (RS - 1);
    int b = blockIdx.x;
    int cnt = bcur[b * 16]; if (cnt > CAP) cnt = CAP;
    const size_t base = (size_t)b * CAP;

    for (int i = t; i < RS * NTILE; i += TPB_P) (&hist[0][0])[i] = 0;
    for (int i = t; i < NPB; i += TPB_P) deg[i] = 0;
    __syncthreads();
    for (int i = t; i < cnt; i += TPB_P) {
        int r = grecU[base + i];
        lbuf[i] = r;
        atomicAdd(&deg[r & (NPB - 1)], 1);
        atomicAdd(&hist[g][((unsigned)r) >> 23], 1);
    }
    __syncthreads();
    if (t < NTILE) {
        int c = 0;
#pragma unroll
        for (int r = 0; r < RS; r++) c += hist[r][t];
        tot[t] = c;
    }
    __syncthreads();
    if (t == 0) {
        int run = 0;
#pragma unroll
        for (int k = 0; k < NTILE; k++) { lstart[k] = run; run += tot[k]; }
    }
    __syncthreads();
    if (t < NTILE) {
        int run = lstart[t];
#pragma unroll
        for (int r = 0; r < RS; r++) { curp[r][t] = run; run += hist[r][t]; }
    }
    __syncthreads();
    // scatter directly to global sorted positions (4B writes, L2-absorbed)
    for (int i = t; i < cnt; i += TPB_P) {
        int r = lbuf[i];
        int p = atomicAdd(&curp[g][((unsigned)r) >> 23], 1);
        grec[base + p] = r;
    }
    __syncthreads();   // lbuf reads done -> safe to overlay sW

    // ---- fused h0: dinv + hp = fp8(dinv * x @ W1^T) for own 1024 nodes ----
    float* sW = (float*)lbuf;
    if (t < 256) sW[t] = W1[t];
    __syncthreads();
    int nodeBase = b << LOG_NPB;
    for (int i = t; i < NPB; i += TPB_P) {
        int node = nodeBase + i;
        if (node >= N) continue;
        float di = rsqrtf((float)(deg[i] + 1));
        dinv[node] = di;
        ((uint4*)hp)[node] = hp_row(x + (size_t)node * 16, sW, di);
    }
}

// ---------------------------------------------------------------------------
// K_AGG: edge-parallel aggregation + finalize (r8 anchor: 54us, FETCH 61.4MB)
// + fused next-layer h: after finalize, compute hpNext = fp8(dinv * z @
// Wnext^T) for own nodes (z re-read L2-hot; hp double-buffered so this
// layer's gathers -- reading hp32 -- never race the hpNext writes).
__global__ __launch_bounds__(TPB_A, 4) void k_agg(const int* __restrict__ bcur,
                                                  const int* __restrict__ grec,
                                                  const float* __restrict__ dinv,
                                                  const unsigned* __restrict__ hp32,
                                                  const float* __restrict__ b,
                                                  const float* __restrict__ xc,
                                                  float* __restrict__ z,
                                                  float* __restrict__ partial,
                                                  const float* __restrict__ Wnext,
                                                  unsigned* __restrict__ hpNext,
                                                  int nb, int N) {
    __shared__ unsigned long long accP[8 * NPB];   // 64 KB; overlays later
    int t = threadIdx.x;
    int bkt = blockIdx.x;
    int cnt = bcur[bkt * 16]; if (cnt > CAP) cnt = CAP;
    const int nodeBase = bkt << LOG_NPB;
    const size_t recBase = (size_t)bkt * CAP;

    for (int i = t; i < 8 * NPB; i += TPB_A) accP[i] = 0ull;
    __syncthreads();

    // ---- Phase 1: edge-parallel scatter (packed biased u64 atomics) ----
    int q = t & 3;
    int gi = t >> 2;
    int p0 = q * 2;
    int p1 = q * 2 + 1;
    int base = 0;
    for (; base + 512 <= cnt; base += 512) {
        int rec[4];
#pragma unroll
        for (int u = 0; u < 4; u++) rec[u] = grec[recBase + base + u * 128 + gi];
        unsigned w[4];
#pragma unroll
        for (int u = 0; u < 4; u++)
            w[u] = hp32[(size_t)(((unsigned)rec[u]) >> LOG_NPB) * 4 + q];
#pragma unroll
        for (int u = 0; u < 4; u++) {
            int dl = rec[u] & (NPB - 1);
            float f0, f1, f2, f3;
            fp8_dec4(w[u], f0, f1, f2, f3);
            atomicAdd(&accP[p0 * NPB + (dl ^ p0)], pack2(f0, f1));
            atomicAdd(&accP[p1 * NPB + (dl ^ p1)], pack2(f2, f3));
        }
    }
    for (int e = base + gi; e < cnt; e += 128) {
        int rec = grec[recBase + e];
        unsigned w = hp32[(size_t)(((unsigned)rec) >> LOG_NPB) * 4 + q];
        int dl = rec & (NPB - 1);
        float f0, f1, f2, f3;
        fp8_dec4(w, f0, f1, f2, f3);
        atomicAdd(&accP[p0 * NPB + (dl ^ p0)], pack2(f0, f1));
        atomicAdd(&accP[p1 * NPB + (dl ^ p1)], pack2(f2, f3));
    }
    __syncthreads();

    // ---- Phase 2: finalize rows (16 lanes per row, 32 row-groups) ----
    const unsigned char* hpB = (const unsigned char*)hp32;
    const int* accI32 = (const int*)accP;
    int j = t & 15;
    int g0 = t >> 4;
    int pj = j >> 1;
    int hj = j & 1;
    float bj = b[j];
    float accW[16];
#pragma unroll
    for (int k = 0; k < 16; k++) accW[k] = 0.f;
    float accB = 0.f;

    for (int i = g0; i < NPB; i += 32) {
        int node = nodeBase + i;
        if (node >= N) break;
        float di = dinv[node];
        int cdeg = (int)rintf(1.0f / (di * di)) - 1;
        int raw = accI32[(pj * NPB + (i ^ pj)) * 2 + hj];
        int ai = raw - cdeg * FXBIAS;
        float sv = fp8_dec(hpB[(size_t)node * 16 + j]);
        float aj = fmaf((float)ai, FXSI, sv);
        float zj = fmaxf(fmaf(di, aj, bj), 0.f);
        z[(size_t)node * 16 + j] = zj;
        float wdj = 4.f * zj * zj;
        accB += wdj;
        const float4* xrow = (const float4*)(xc + (size_t)node * 16);
        float4 x0 = xrow[0], x1 = xrow[1], x2 = xrow[2], x3 = xrow[3];
        accW[0]  = fmaf(x0.x, wdj, accW[0]);  accW[1]  = fmaf(x0.y, wdj, accW[1]);
        accW[2]  = fmaf(x0.z, wdj, accW[2]);  accW[3]  = fmaf(x0.w, wdj, accW[3]);
        accW[4]  = fmaf(x1.x, wdj, accW[4]);  accW[5]  = fmaf(x1.y, wdj, accW[5]);
        accW[6]  = fmaf(x1.z, wdj, accW[6]);  accW[7]  = fmaf(x1.w, wdj, accW[7]);
        accW[8]  = fmaf(x2.x, wdj, accW[8]);  accW[9]  = fmaf(x2.y, wdj, accW[9]);
        accW[10] = fmaf(x2.z, wdj, accW[10]); accW[11] = fmaf(x2.w, wdj, accW[11]);
        accW[12] = fmaf(x3.x, wdj, accW[12]); accW[13] = fmaf(x3.y, wdj, accW[13]);
        accW[14] = fmaf(x3.z, wdj, accW[14]); accW[15] = fmaf(x3.w, wdj, accW[15]);
    }
    __syncthreads();   // all accP reads done -> safe to alias red onto accP

    float (*red)[17] = (float (*)[17])accP;   // 34816 B overlay
#pragma unroll
    for (int k = 0; k < 16; k++) red[t][k] = accW[k];
    red[t][16] = accB;
    __syncthreads();
    if (t < 256) {
        int kk = t >> 4;
        int jj = t & 15;
        float s = 0.f;
#pragma unroll
        for (int g2 = 0; g2 < 32; g2++) s += red[g2 * 16 + jj][kk];
        partial[(size_t)(kk * 16 + jj) * nb + bkt] = s;
    }
    if (t < 16) {
        float sb = 0.f;
#pragma unroll
        for (int g2 = 0; g2 < 32; g2++) sb += red[g2 * 16 + t][16];
        partial[(size_t)(256 + t) * nb + bkt] = sb;
    }

    // ---- Phase 3 (fused next-layer h): hpNext = fp8(dinv * z @ Wnext^T) ----
    if (Wnext != nullptr) {
        __syncthreads();   // red reads done -> safe to overlay sW
        float* sW = (float*)accP;
        if (t < 256) sW[t] = Wnext[t];
        __syncthreads();
        for (int i = t; i < NPB; i += TPB_A) {
            int node = nodeBase + i;
            if (node >= N) continue;
            ((uint4*)hpNext)[node] = hp_row(z + (size_t)node * 16, sW, dinv[node]);
        }
    }
}

// K5b: one 64-lane wave per (layer,elem), 52 blocks: memory-parallel sums.
// (r7 lesson: single-block merged reduce is latency-bound at 163us.)
__global__ __launch_bounds__(TPB) void k_reduce(const float* __restrict__ partial,
                                                float* __restrict__ acc,
                                                int nb, int total) {
    int wid = (blockIdx.x * blockDim.x + threadIdx.x) >> 6;
    int lane = threadIdx.x & 63;
    if (wid >= total) return;
    const float* p = partial + (size_t)wid * nb;
    float s = 0.f;
    for (int b = lane; b < nb; b += 64) s += p[b];
#pragma unroll
    for (int off = 32; off > 0; off >>= 1) s += __shfl_down(s, off, 64);
    if (lane == 0) acc[wid] = s;
}

// ---------------------------------------------------------------------------
__device__ __forceinline__ float local_loss_f(float g, int positive) {
    const float t = 0.0f;
    if (positive) {
        if (g > t + 10.f) return 0.f;
        if (g < t - 10.f) return t - g;
        return log1pf(expf(t - g));
    } else {
        if (g > t + 10.f) return t + g;
        if (g < t - 10.f) return 0.f;
        return log1pf(expf(g + t));
    }
}

__global__ void k_final(const float* __restrict__ W1, const float* __restrict__ b1,
                        const float* __restrict__ acc, const int* __restrict__ positive,
                        float* __restrict__ outv) {
    int t = threadIdx.x;
    if (t < 256) {
        int jj = t >> 4, kk = t & 15;   // Wc[jj][kk] -= LR * dW[kk][jj]
        float s = 0.f;
#pragma unroll
        for (int l = 0; l < 3; l++) s += acc[l * 272 + kk * 16 + jj];
        outv[1 + t] = W1[t] - LRATE * s;
    }
    if (t < 16) {
        float s = 0.f;
#pragma unroll
        for (int l = 0; l < 3; l++) s += acc[l * 272 + 256 + t];
        outv[257 + t] = b1[t] - LRATE * s;
    }
    if (t == 0) {
        int pos = positive[0];
        float agg = 0.f;
#pragma unroll
        for (int l = 0; l < 3; l++) {
            float g = 0.f;
#pragma unroll
            for (int jj = 0; jj < 16; jj++) g += acc[l * 272 + 256 + jj];
            g *= (1.0f / 64.0f);
            agg += local_loss_f(g, pos);
        }
        outv[0] = agg;
    }
}

extern "C" void kernel_launch(void* const* d_in, const int* in_sizes, int n_in,
                              void* d_out, int out_size, void* d_ws, size_t ws_size,
                              hipStream_t stream) {
    const float* x  = (const float*)d_in[0];
    const int*   ei = (const int*)d_in[1];
    const float* W1 = (const float*)d_in[2];
    const float* b1 = (const float*)d_in[3];
    const float* W2 = (const float*)d_in[4];
    const float* b2 = (const float*)d_in[5];
    const float* W3 = (const float*)d_in[6];
    const float* b3 = (const float*)d_in[7];
    const int* positive = (const int*)d_in[8];
    float* outv = (float*)d_out;

    const int N = in_sizes[0] / 16;
    const int E = in_sizes[1] / 2;
    const int nbuck = (N + NPB - 1) >> LOG_NPB;         // 489 for N=500k
    const int nsuper = (N + (1 << LOG_SUP) - 1) >> LOG_SUP;   // 62
    const int nbpad = nsuper * NS2;                     // 496

    // Workspace carve-out (256B aligned).
    char* ws = (char*)d_ws;
    size_t off = 0;
    auto carve = [&](size_t bytes) -> void* {
        void* p = ws + off;
        off = (off + bytes + 255) & ~(size_t)255;
        return p;
    };
    int*   bcur   = (int*)  carve((size_t)(nbpad + NS1) * 16 * 4);
    int*   bcur1  = bcur + (size_t)nbpad * 16;
    int*   grec   = (int*)  carve((size_t)nbpad * CAP * 4);   // sorted, lives all layers
    float* dinv   = (float*)carve((size_t)N * 4);
    float* acc    = (float*)carve(3 * 272 * 4);
    float* part   = (float*)carve((size_t)3 * 272 * nbuck * 4);
    unsigned* hpA = (unsigned*)carve((size_t)N * 16);         // fp8 rows, 8 MB
    unsigned* hpB = (unsigned*)carve((size_t)N * 16);         // double buffer
    // grecU (28.4MB, dead after k_sort) aliases P1 (first written by agg L0).
    float* P1     = (float*)carve((size_t)N * 64);
    int*   grecU  = (int*)P1;
    // grec1 (22.3MB, dead after k_part2) aliases P2 (first written by agg L1).
    float* P2     = (float*)carve((size_t)N * 64);
    int*   grec1  = (int*)P2;

    hipMemsetAsync(bcur, 0, (size_t)(nbpad + NS1) * 16 * 4, stream);

    const int* src = ei;
    const int* dst = ei + E;

    // --- Two-level partition + sort(+h0) (once, reused 3x) ---
    int p1Blocks = (E + CHUNK - 1) / CHUNK;
    k_part1<<<p1Blocks, TPB_P, 0, stream>>>(src, dst, bcur1, grec1, E);
    dim3 g2(nsuper, CAP1 / CHUNK);     // (62, 22)
    k_part2<<<g2, TPB_P, 0, stream>>>(bcur1, grec1, bcur, grecU);
    k_sort<<<nbuck, TPB_P, 0, stream>>>(bcur, grecU, grec, dinv, x, W1, hpA, N);

    // --- 3 layers; k_h for layers 1,2 fused into the previous k_agg ---
    // L0: gather hpA, z->P1, produce hpB (W2).  L1: gather hpB, z->P2,
    // produce hpA (W3).  L2: gather hpA, z->P1, no next.
    k_agg<<<nbuck, TPB_A, 0, stream>>>(bcur, grec, dinv, hpA, b1, x,  P1,
                                       part + (size_t)0 * 272 * nbuck,
                                       W2, hpB, nbuck, N);
    k_agg<<<nbuck, TPB_A, 0, stream>>>(bcur, grec, dinv, hpB, b2, P1, P2,
                                       part + (size_t)1 * 272 * nbuck,
                                       W3, hpA, nbuck, N);
    k_agg<<<nbuck, TPB_A, 0, stream>>>(bcur, grec, dinv, hpA, b3, P2, P1,
                                       part + (size_t)2 * 272 * nbuck,
                                       nullptr, nullptr, nbuck, N);

    int totalElems = 3 * 272;
    k_reduce<<<(totalElems * 64 + TPB - 1) / TPB, TPB, 0, stream>>>(part, acc, nbuck, totalElems);
    k_final<<<1, 256, 0, stream>>>(W1, b1, acc, positive, outv);
}

// Round 12
// 409.892 us; speedup vs baseline: 1.6035x; 1.6035x over previous
//
#include <hip/hip_runtime.h>
#include <math.h>

#define TPB 256
#define TPB_P 512
#define TPB_A 512            // k_agg: 64KB acc -> 2 blocks/CU, 16 waves/CU (R4 measured best)
#define LRATE 0.005f

// Final bucketing: 1024 nodes per bucket (round-4 measured optimum)
#define LOG_NPB 10
#define NPB (1 << LOG_NPB)
#define CAP 14336            // mean ~10225 edges/bucket; +40 sigma

// Two-level partition (r5 lesson: short scatter runs -> 4x write amp)
#define LOG_SUP 13
#define NS1 64               // level-1 bins: dst>>13
#define CAP1 90112           // 22*4096; mean 81920, +28 sigma
#define NS2 8                // level-2 bins
#define CHUNK 4096
#define CPT (CHUNK / TPB_P)  // 8
#define R1 4                 // hist/cursor replication (part1)
#define R2 8                 // (part2)
#define RS 4                 // (sort)
#define NTILE 64             // src-tile = src>>13 == rec>>23

// fixed-point scale (LDS int atomics native; float LDS atomicAdd = CAS loop)
#define FXS  65536.0f
#define FXSI (1.0f / 65536.0f)
#define FXBIAS (1 << 20)     // per-addend bias: positive halves, no carry

// ---------------------------------------------------------------------------
#if __has_builtin(__builtin_amdgcn_cvt_f32_fp8) && __has_builtin(__builtin_amdgcn_cvt_pk_fp8_f32)
__device__ __forceinline__ float fp8_dec(unsigned char v) {
    return __builtin_amdgcn_cvt_f32_fp8((int)v, 0);
}
__device__ __forceinline__ unsigned fp8_pk4(float a, float b, float c, float d) {
    int w = __builtin_amdgcn_cvt_pk_fp8_f32(a, b, 0, false);
    w = __builtin_amdgcn_cvt_pk_fp8_f32(c, d, w, true);
    return (unsigned)w;
}
#else
__device__ __forceinline__ unsigned char fp8_enc1(float f) {
    unsigned u = __float_as_uint(f);
    unsigned s = (u >> 24) & 0x80u;
    u &= 0x7FFFFFFFu;
    if (u >= 0x43E00000u) return (unsigned char)(s | 0x7E);
    if (u < 0x3C800000u) {
        float a = __uint_as_float(u);
        int m = (int)rintf(a * 512.f);
        return (unsigned char)(s | (unsigned)m);
    }
    unsigned mant = u & 0x7FFFFFu;
    unsigned rest = mant & 0xFFFFFu;
    unsigned keep = u >> 20;
    keep += (rest > 0x80000u || (rest == 0x80000u && (keep & 1u))) ? 1u : 0u;
    int eb = (int)(keep >> 3) - 127 + 7;
    return (unsigned char)(s | (unsigned)((eb << 3) | (int)(keep & 7u)));
}
__device__ __forceinline__ float fp8_dec(unsigned char v) {
    unsigned s = ((unsigned)(v & 0x80u)) << 24;
    unsigned e = (v >> 3) & 0xFu;
    unsigned m = v & 7u;
    if (e == 0) {
        float r = (float)m * 0.001953125f;
        return (v & 0x80u) ? -r : r;
    }
    return __uint_as_float(s | ((e + 120u) << 23) | (m << 20));
}
__device__ __forceinline__ unsigned fp8_pk4(float a, float b, float c, float d) {
    return (unsigned)fp8_enc1(a) | ((unsigned)fp8_enc1(b) << 8) |
           ((unsigned)fp8_enc1(c) << 16) | ((unsigned)fp8_enc1(d) << 24);
}
#endif

#if __has_builtin(__builtin_amdgcn_cvt_pk_f32_fp8)
typedef float __attribute__((ext_vector_type(2))) f32x2;
__device__ __forceinline__ void fp8_dec4(unsigned w, float& a, float& b, float& c, float& d) {
    f32x2 lo = __builtin_amdgcn_cvt_pk_f32_fp8((int)w, false);
    f32x2 hi = __builtin_amdgcn_cvt_pk_f32_fp8((int)w, true);
    a = lo[0]; b = lo[1]; c = hi[0]; d = hi[1];
}
#else
__device__ __forceinline__ void fp8_dec4(unsigned w, float& a, float& b, float& c, float& d) {
    a = fp8_dec((unsigned char)(w & 0xFFu));
    b = fp8_dec((unsigned char)((w >> 8) & 0xFFu));
    c = fp8_dec((unsigned char)((w >> 16) & 0xFFu));
    d = fp8_dec((unsigned char)((w >> 24) & 0xFFu));
}
#endif

__device__ __forceinline__ unsigned long long pack2(float f0, float f1) {
    unsigned lo = (unsigned)(FXBIAS + (int)(f0 * FXS));
    unsigned hi = (unsigned)(FXBIAS + (int)(f1 * FXS));
    return (unsigned long long)lo | ((unsigned long long)hi << 32);
}

// compute one fp8 hp row: hp[node] = fp8(di * xrow @ W^T), W in LDS
__device__ __forceinline__ uint4 hp_row(const float* __restrict__ xrow,
                                        const float* __restrict__ sW, float di) {
    float xv[16];
    const float4* xr = (const float4*)xrow;
#pragma unroll
    for (int q = 0; q < 4; q++) {
        float4 v = xr[q];
        xv[4*q+0] = v.x; xv[4*q+1] = v.y; xv[4*q+2] = v.z; xv[4*q+3] = v.w;
    }
    float hv[16];
#pragma unroll
    for (int j = 0; j < 16; j++) {
        float s = 0.f;
#pragma unroll
        for (int k = 0; k < 16; k++) s = fmaf(xv[k], sW[j*16 + k], s);
        hv[j] = di * s;
    }
    uint4 w;
    w.x = fp8_pk4(hv[0],  hv[1],  hv[2],  hv[3]);
    w.y = fp8_pk4(hv[4],  hv[5],  hv[6],  hv[7]);
    w.z = fp8_pk4(hv[8],  hv[9],  hv[10], hv[11]);
    w.w = fp8_pk4(hv[12], hv[13], hv[14], hv[15]);
    return w;
}

// ---------------------------------------------------------------------------
// K_PART1: level-1 partition by super-bucket (dst >> 13, 64 bins; x4 repl).
__global__ __launch_bounds__(TPB_P) void k_part1(const int* __restrict__ src,
                                                 const int* __restrict__ dst,
                                                 int* __restrict__ bcur1,
                                                 int* __restrict__ grec1,
                                                 int E) {
    __shared__ int hist[R1][NS1];
    __shared__ int lcur[R1][NS1];
    __shared__ int lstart[NS1], tot[NS1], gbase[NS1];
    __shared__ int lbuf[CHUNK];
    __shared__ unsigned char bbuf[CHUNK];
    int t = threadIdx.x;
    int g = t & (R1 - 1);
    int chunkBase = blockIdx.x * CHUNK;
    for (int i = t; i < R1 * NS1; i += TPB_P) (&hist[0][0])[i] = 0;
    __syncthreads();

    int myb[CPT], myrec[CPT];
#pragma unroll
    for (int k = 0; k < CPT; k++) {
        int e = chunkBase + k * TPB_P + t;
        if (e < E) {
            int d = dst[e];
            int s = src[e];
            myb[k] = d >> LOG_SUP;
            myrec[k] = (s << LOG_SUP) | (d & ((1 << LOG_SUP) - 1));
            atomicAdd(&hist[g][myb[k]], 1);
        } else myb[k] = -1;
    }
    __syncthreads();
    if (t < NS1) {
        int s = 0;
#pragma unroll
        for (int r = 0; r < R1; r++) s += hist[r][t];
        tot[t] = s;
    }
    __syncthreads();
    if (t == 0) {
        int run = 0;
        for (int b = 0; b < NS1; b++) { lstart[b] = run; run += tot[b]; }
    }
    __syncthreads();
    if (t < NS1) {
        int run = lstart[t];
#pragma unroll
        for (int r = 0; r < R1; r++) { lcur[r][t] = run; run += hist[r][t]; }
        if (tot[t] > 0) gbase[t] = atomicAdd(&bcur1[t * 16], tot[t]);
    }
    __syncthreads();
#pragma unroll
    for (int k = 0; k < CPT; k++) {
        if (myb[k] >= 0) {
            int p = atomicAdd(&lcur[g][myb[k]], 1);
            lbuf[p] = myrec[k];
            bbuf[p] = (unsigned char)myb[k];
        }
    }
    __syncthreads();
    int total = E - chunkBase; if (total > CHUNK) total = CHUNK;
    for (int p = t; p < total; p += TPB_P) {
        int b = (int)bbuf[p];
        int pos = gbase[b] + (p - lstart[b]);
        if (pos < CAP1) grec1[(size_t)b * CAP1 + pos] = lbuf[p];
    }
}

// K_PART2: level-2 partition of each super-bucket into its 8 final buckets.
__global__ __launch_bounds__(TPB_P) void k_part2(const int* __restrict__ bcur1,
                                                 const int* __restrict__ grec1,
                                                 int* __restrict__ bcur,
                                                 int* __restrict__ grecU) {
    __shared__ int hist[R2][NS2];
    __shared__ int lcur[R2][NS2];
    __shared__ int lstart[NS2], tot[NS2], gbase[NS2];
    __shared__ int lbuf[CHUNK];
    __shared__ unsigned char bbuf[CHUNK];
    int t = threadIdx.x;
    int g = t & (R2 - 1);
    int s = blockIdx.x;
    int cnt1 = bcur1[s * 16]; if (cnt1 > CAP1) cnt1 = CAP1;
    int chunkBase = blockIdx.y * CHUNK;
    if (chunkBase >= cnt1) return;             // uniform per block
    int total = cnt1 - chunkBase; if (total > CHUNK) total = CHUNK;
    for (int i = t; i < R2 * NS2; i += TPB_P) (&hist[0][0])[i] = 0;
    __syncthreads();

    int myb[CPT], myrec[CPT];
#pragma unroll
    for (int k = 0; k < CPT; k++) {
        int i = chunkBase + k * TPB_P + t;
        if (i < cnt1) {
            int r = grec1[(size_t)s * CAP1 + i];
            int sub = (r >> LOG_NPB) & (NS2 - 1);
            myb[k] = sub;
            myrec[k] = (int)((((unsigned)r) >> LOG_SUP) << LOG_NPB) | (r & (NPB - 1));
            atomicAdd(&hist[g][sub], 1);
        } else myb[k] = -1;
    }
    __syncthreads();
    if (t < NS2) {
        int c = 0;
#pragma unroll
        for (int r = 0; r < R2; r++) c += hist[r][t];
        tot[t] = c;
    }
    __syncthreads();
    if (t == 0) {
        int run = 0;
        for (int b = 0; b < NS2; b++) { lstart[b] = run; run += tot[b]; }
    }
    __syncthreads();
    if (t < NS2) {
        int run = lstart[t];
#pragma unroll
        for (int r = 0; r < R2; r++) { lcur[r][t] = run; run += hist[r][t]; }
        if (tot[t] > 0) gbase[t] = atomicAdd(&bcur[(s * NS2 + t) * 16], tot[t]);
    }
    __syncthreads();
#pragma unroll
    for (int k = 0; k < CPT; k++) {
        if (myb[k] >= 0) {
            int p = atomicAdd(&lcur[g][myb[k]], 1);
            lbuf[p] = myrec[k];
            bbuf[p] = (unsigned char)myb[k];
        }
    }
    __syncthreads();
    for (int p = t; p < total; p += TPB_P) {
        int b = (int)bbuf[p];
        int pos = gbase[b] + (p - lstart[b]);
        if (pos < CAP) grecU[(size_t)(s * NS2 + b) * CAP + pos] = lbuf[p];
    }
}

// K_SORT(+h0): per-bucket counting sort by src-tile, out-of-place
// grecU -> grec; then deg -> dinv AND layer-0 hp rows for own nodes.
// (h0 fusion is safe: own-bucket reads, no sweep-locality to pollute, and
// it ends by writing hp -> L2-warm for agg-L0 exactly as the old k_h did.
// The r11 failure was the OTHER fusion -- h inside k_agg.)
__global__ __launch_bounds__(TPB_P) void k_sort(const int* __restrict__ bcur,
                                                const int* __restrict__ grecU,
                                                int* __restrict__ grec,
                                                float* __restrict__ dinv,
                                                const float* __restrict__ x,
                                                const float* __restrict__ W1,
                                                unsigned* __restrict__ hp, int N) {
    __shared__ int lbuf[CAP];     // 57344 B (sW overlays after scatter)
    __shared__ int deg[NPB];      // 4096 B
    __shared__ int hist[RS][NTILE];
    __shared__ int curp[RS][NTILE];
    __shared__ int lstart[NTILE], tot[NTILE];
    int t = threadIdx.x;
    int g = t & (RS - 1);
    int b = blockIdx.x;
    int cnt = bcur[b * 16]; if (cnt > CAP) cnt = CAP;
    const size_t base = (size_t)b * CAP;

    for (int i = t; i < RS * NTILE; i += TPB_P) (&hist[0][0])[i] = 0;
    for (int i = t; i < NPB; i += TPB_P) deg[i] = 0;
    __syncthreads();
    for (int i = t; i < cnt; i += TPB_P) {
        int r = grecU[base + i];
        lbuf[i] = r;
        atomicAdd(&deg[r & (NPB - 1)], 1);
        atomicAdd(&hist[g][((unsigned)r) >> 23], 1);
    }
    __syncthreads();
    if (t < NTILE) {
        int c = 0;
#pragma unroll
        for (int r = 0; r < RS; r++) c += hist[r][t];
        tot[t] = c;
    }
    __syncthreads();
    if (t == 0) {
        int run = 0;
#pragma unroll
        for (int k = 0; k < NTILE; k++) { lstart[k] = run; run += tot[k]; }
    }
    __syncthreads();
    if (t < NTILE) {
        int run = lstart[t];
#pragma unroll
        for (int r = 0; r < RS; r++) { curp[r][t] = run; run += hist[r][t]; }
    }
    __syncthreads();
    // scatter directly to global sorted positions (4B writes, L2-absorbed)
    for (int i = t; i < cnt; i += TPB_P) {
        int r = lbuf[i];
        int p = atomicAdd(&curp[g][((unsigned)r) >> 23], 1);
        grec[base + p] = r;
    }
    __syncthreads();   // lbuf reads done -> safe to overlay sW

    // ---- fused h0: dinv + hp = fp8(dinv * x @ W1^T) for own 1024 nodes ----
    float* sW = (float*)lbuf;
    if (t < 256) sW[t] = W1[t];
    __syncthreads();
    int nodeBase = b << LOG_NPB;
    for (int i = t; i < NPB; i += TPB_P) {
        int node = nodeBase + i;
        if (node >= N) continue;
        float di = rsqrtf((float)(deg[i] + 1));
        dinv[node] = di;
        ((uint4*)hp)[node] = hp_row(x + (size_t)node * 16, sW, di);
    }
}

// ---------------------------------------------------------------------------
// K3: hp = fp8_e4m3( dinv * (x @ W.T) ) — separate dispatch for layers 1,2.
// (r11 lesson: this dispatch is load-bearing — it acts as a traffic barrier
// and hp L2-preload for the following k_agg's in-phase sweep.)
__global__ __launch_bounds__(TPB) void k_h(const float* __restrict__ xc,
                                           const float* __restrict__ W,
                                           const float* __restrict__ dinv,
                                           unsigned* __restrict__ hp, int n) {
    __shared__ float sW[256];
    if (threadIdx.x < 256) sW[threadIdx.x] = W[threadIdx.x];
    __syncthreads();
    int i = blockIdx.x * blockDim.x + threadIdx.x;
    int stride = gridDim.x * blockDim.x;
    for (; i < n; i += stride) {
        ((uint4*)hp)[i] = hp_row(xc + (size_t)i * 16, sW, dinv[i]);
    }
}

// ---------------------------------------------------------------------------
// K_AGG: edge-parallel aggregation + finalize, ONE block per 1024-node
// bucket. UNCHANGED r8 anchor: 54us, FETCH 61.4MB, 3.19M conflicts.
__global__ __launch_bounds__(TPB_A, 4) void k_agg(const int* __restrict__ bcur,
                                                  const int* __restrict__ grec,
                                                  const float* __restrict__ dinv,
                                                  const unsigned* __restrict__ hp32,
                                                  const float* __restrict__ b,
                                                  const float* __restrict__ xc,
                                                  float* __restrict__ z,
                                                  float* __restrict__ partial,
                                                  int nb, int N) {
    __shared__ unsigned long long accP[8 * NPB];   // 64 KB; red overlay later
    int t = threadIdx.x;
    int bkt = blockIdx.x;
    int cnt = bcur[bkt * 16]; if (cnt > CAP) cnt = CAP;
    const int nodeBase = bkt << LOG_NPB;
    const size_t recBase = (size_t)bkt * CAP;

    for (int i = t; i < 8 * NPB; i += TPB_A) accP[i] = 0ull;
    __syncthreads();

    // ---- Phase 1: edge-parallel scatter (packed biased u64 atomics) ----
    int q = t & 3;
    int gi = t >> 2;
    int p0 = q * 2;
    int p1 = q * 2 + 1;
    int base = 0;
    for (; base + 512 <= cnt; base += 512) {
        int rec[4];
#pragma unroll
        for (int u = 0; u < 4; u++) rec[u] = grec[recBase + base + u * 128 + gi];
        unsigned w[4];
#pragma unroll
        for (int u = 0; u < 4; u++)
            w[u] = hp32[(size_t)(((unsigned)rec[u]) >> LOG_NPB) * 4 + q];
#pragma unroll
        for (int u = 0; u < 4; u++) {
            int dl = rec[u] & (NPB - 1);
            float f0, f1, f2, f3;
            fp8_dec4(w[u], f0, f1, f2, f3);
            atomicAdd(&accP[p0 * NPB + (dl ^ p0)], pack2(f0, f1));
            atomicAdd(&accP[p1 * NPB + (dl ^ p1)], pack2(f2, f3));
        }
    }
    for (int e = base + gi; e < cnt; e += 128) {
        int rec = grec[recBase + e];
        unsigned w = hp32[(size_t)(((unsigned)rec) >> LOG_NPB) * 4 + q];
        int dl = rec & (NPB - 1);
        float f0, f1, f2, f3;
        fp8_dec4(w, f0, f1, f2, f3);
        atomicAdd(&accP[p0 * NPB + (dl ^ p0)], pack2(f0, f1));
        atomicAdd(&accP[p1 * NPB + (dl ^ p1)], pack2(f2, f3));
    }
    __syncthreads();

    // ---- Phase 2: finalize rows (16 lanes per row, 32 row-groups) ----
    const unsigned char* hpB = (const unsigned char*)hp32;
    const int* accI32 = (const int*)accP;
    int j = t & 15;
    int g0 = t >> 4;
    int pj = j >> 1;
    int hj = j & 1;
    float bj = b[j];
    float accW[16];
#pragma unroll
    for (int k = 0; k < 16; k++) accW[k] = 0.f;
    float accB = 0.f;

    for (int i = g0; i < NPB; i += 32) {
        int node = nodeBase + i;
        if (node >= N) break;
        float di = dinv[node];
        int cdeg = (int)rintf(1.0f / (di * di)) - 1;
        int raw = accI32[(pj * NPB + (i ^ pj)) * 2 + hj];
        int ai = raw - cdeg * FXBIAS;
        float sv = fp8_dec(hpB[(size_t)node * 16 + j]);
        float aj = fmaf((float)ai, FXSI, sv);
        float zj = fmaxf(fmaf(di, aj, bj), 0.f);
        z[(size_t)node * 16 + j] = zj;
        float wdj = 4.f * zj * zj;
        accB += wdj;
        const float4* xrow = (const float4*)(xc + (size_t)node * 16);
        float4 x0 = xrow[0], x1 = xrow[1], x2 = xrow[2], x3 = xrow[3];
        accW[0]  = fmaf(x0.x, wdj, accW[0]);  accW[1]  = fmaf(x0.y, wdj, accW[1]);
        accW[2]  = fmaf(x0.z, wdj, accW[2]);  accW[3]  = fmaf(x0.w, wdj, accW[3]);
        accW[4]  = fmaf(x1.x, wdj, accW[4]);  accW[5]  = fmaf(x1.y, wdj, accW[5]);
        accW[6]  = fmaf(x1.z, wdj, accW[6]);  accW[7]  = fmaf(x1.w, wdj, accW[7]);
        accW[8]  = fmaf(x2.x, wdj, accW[8]);  accW[9]  = fmaf(x2.y, wdj, accW[9]);
        accW[10] = fmaf(x2.z, wdj, accW[10]); accW[11] = fmaf(x2.w, wdj, accW[11]);
        accW[12] = fmaf(x3.x, wdj, accW[12]); accW[13] = fmaf(x3.y, wdj, accW[13]);
        accW[14] = fmaf(x3.z, wdj, accW[14]); accW[15] = fmaf(x3.w, wdj, accW[15]);
    }
    __syncthreads();   // all accP reads done -> safe to alias red onto accP

    float (*red)[17] = (float (*)[17])accP;   // 34816 B overlay
#pragma unroll
    for (int k = 0; k < 16; k++) red[t][k] = accW[k];
    red[t][16] = accB;
    __syncthreads();
    if (t < 256) {
        int kk = t >> 4;
        int jj = t & 15;
        float s = 0.f;
#pragma unroll
        for (int g2 = 0; g2 < 32; g2++) s += red[g2 * 16 + jj][kk];
        partial[(size_t)(kk * 16 + jj) * nb + bkt] = s;
    }
    if (t < 16) {
        float sb = 0.f;
#pragma unroll
        for (int g2 = 0; g2 < 32; g2++) sb += red[g2 * 16 + t][16];
        partial[(size_t)(256 + t) * nb + bkt] = sb;
    }
}

// K5b: one 64-lane wave per (layer,elem), 52 blocks: memory-parallel sums.
// (r7 lesson: single-block merged reduce is latency-bound at 163us.)
__global__ __launch_bounds__(TPB) void k_reduce(const float* __restrict__ partial,
                                                float* __restrict__ acc,
                                                int nb, int total) {
    int wid = (blockIdx.x * blockDim.x + threadIdx.x) >> 6;
    int lane = threadIdx.x & 63;
    if (wid >= total) return;
    const float* p = partial + (size_t)wid * nb;
    float s = 0.f;
    for (int b = lane; b < nb; b += 64) s += p[b];
#pragma unroll
    for (int off = 32; off > 0; off >>= 1) s += __shfl_down(s, off, 64);
    if (lane == 0) acc[wid] = s;
}

// ---------------------------------------------------------------------------
__device__ __forceinline__ float local_loss_f(float g, int positive) {
    const float t = 0.0f;
    if (positive) {
        if (g > t + 10.f) return 0.f;
        if (g < t - 10.f) return t - g;
        return log1pf(expf(t - g));
    } else {
        if (g > t + 10.f) return t + g;
        if (g < t - 10.f) return 0.f;
        return log1pf(expf(g + t));
    }
}

__global__ void k_final(const float* __restrict__ W1, const float* __restrict__ b1,
                        const float* __restrict__ acc, const int* __restrict__ positive,
                        float* __restrict__ outv) {
    int t = threadIdx.x;
    if (t < 256) {
        int jj = t >> 4, kk = t & 15;   // Wc[jj][kk] -= LR * dW[kk][jj]
        float s = 0.f;
#pragma unroll
        for (int l = 0; l < 3; l++) s += acc[l * 272 + kk * 16 + jj];
        outv[1 + t] = W1[t] - LRATE * s;
    }
    if (t < 16) {
        float s = 0.f;
#pragma unroll
        for (int l = 0; l < 3; l++) s += acc[l * 272 + 256 + t];
        outv[257 + t] = b1[t] - LRATE * s;
    }
    if (t == 0) {
        int pos = positive[0];
        float agg = 0.f;
#pragma unroll
        for (int l = 0; l < 3; l++) {
            float g = 0.f;
#pragma unroll
            for (int jj = 0; jj < 16; jj++) g += acc[l * 272 + 256 + jj];
            g *= (1.0f / 64.0f);
            agg += local_loss_f(g, pos);
        }
        outv[0] = agg;
    }
}

extern "C" void kernel_launch(void* const* d_in, const int* in_sizes, int n_in,
                              void* d_out, int out_size, void* d_ws, size_t ws_size,
                              hipStream_t stream) {
    const float* x  = (const float*)d_in[0];
    const int*   ei = (const int*)d_in[1];
    const float* W1 = (const float*)d_in[2];
    const float* b1 = (const float*)d_in[3];
    const float* W2 = (const float*)d_in[4];
    const float* b2 = (const float*)d_in[5];
    const float* W3 = (const float*)d_in[6];
    const float* b3 = (const float*)d_in[7];
    const int* positive = (const int*)d_in[8];
    float* outv = (float*)d_out;

    const int N = in_sizes[0] / 16;
    const int E = in_sizes[1] / 2;
    const int nbuck = (N + NPB - 1) >> LOG_NPB;         // 489 for N=500k
    const int nsuper = (N + (1 << LOG_SUP) - 1) >> LOG_SUP;   // 62
    const int nbpad = nsuper * NS2;                     // 496

    // Workspace carve-out (256B aligned).
    char* ws = (char*)d_ws;
    size_t off = 0;
    auto carve = [&](size_t bytes) -> void* {
        void* p = ws + off;
        off = (off + bytes + 255) & ~(size_t)255;
        return p;
    };
    int*   bcur   = (int*)  carve((size_t)(nbpad + NS1) * 16 * 4);
    int*   bcur1  = bcur + (size_t)nbpad * 16;
    int*   grec   = (int*)  carve((size_t)nbpad * CAP * 4);   // sorted, lives all layers
    float* dinv   = (float*)carve((size_t)N * 4);
    float* acc    = (float*)carve(3 * 272 * 4);
    float* part   = (float*)carve((size_t)3 * 272 * nbuck * 4);
    unsigned* hp  = (unsigned*)carve((size_t)N * 16);         // fp8 rows, 8 MB
    // grecU (28.4MB, dead after k_sort) aliases P1 (first written by agg L0).
    float* P1     = (float*)carve((size_t)N * 64);
    int*   grecU  = (int*)P1;
    // grec1 (22.3MB, dead after k_part2) aliases P2 (first written by agg L1).
    float* P2     = (float*)carve((size_t)N * 64);
    int*   grec1  = (int*)P2;

    hipMemsetAsync(bcur, 0, (size_t)(nbpad + NS1) * 16 * 4, stream);

    const int* src = ei;
    const int* dst = ei + E;

    // --- Two-level partition + sort(+h0) (once, reused 3x) ---
    int p1Blocks = (E + CHUNK - 1) / CHUNK;
    k_part1<<<p1Blocks, TPB_P, 0, stream>>>(src, dst, bcur1, grec1, E);
    dim3 g2(nsuper, CAP1 / CHUNK);     // (62, 22)
    k_part2<<<g2, TPB_P, 0, stream>>>(bcur1, grec1, bcur, grecU);
    k_sort<<<nbuck, TPB_P, 0, stream>>>(bcur, grecU, grec, dinv, x, W1, hp, N);

    // --- 3 layers; L0's k_h fused into k_sort, L1/L2 keep separate k_h ---
    int nodeBlocks = (N + TPB - 1) / TPB;

    k_agg<<<nbuck, TPB_A, 0, stream>>>(bcur, grec, dinv, hp, b1, x, P1,
                                       part + (size_t)0 * 272 * nbuck, nbuck, N);
    k_h<<<nodeBlocks, TPB, 0, stream>>>(P1, W2, dinv, hp, N);
    k_agg<<<nbuck, TPB_A, 0, stream>>>(bcur, grec, dinv, hp, b2, P1, P2,
                                       part + (size_t)1 * 272 * nbuck, nbuck, N);
    k_h<<<nodeBlocks, TPB, 0, stream>>>(P2, W3, dinv, hp, N);
    k_agg<<<nbuck, TPB_A, 0, stream>>>(bcur, grec, dinv, hp, b3, P2, P1,
                                       part + (size_t)2 * 272 * nbuck, nbuck, N);

    int totalElems = 3 * 272;
    k_reduce<<<(totalElems * 64 + TPB - 1) / TPB, TPB, 0, stream>>>(part, acc, nbuck, totalElems);
    k_final<<<1, 256, 0, stream>>>(W1, b1, acc, positive, outv);
}